// Round 1
// baseline (1672.329 us; speedup 1.0000x reference)
//
#include <hip/hip_runtime.h>
#include <hip/hip_bf16.h>

typedef __bf16 bf16x8 __attribute__((ext_vector_type(8)));
typedef float  f32x4  __attribute__((ext_vector_type(4)));

#define BM 128
#define BN 128
#define BK 64
#define THREADS 256

__device__ __forceinline__ void gload_lds16(const void* g, void* l) {
  __builtin_amdgcn_global_load_lds(
      (const __attribute__((address_space(1))) void*)g,
      (__attribute__((address_space(3))) void*)l, 16, 0, 0);
}

// ---- fp32 -> bf16 (RNE), 8 elems per thread-iter, grid-stride ----
__global__ void cvt_x_kernel(const float* __restrict__ in, __bf16* __restrict__ out, long n) {
  long i0 = ((long)blockIdx.x * blockDim.x + threadIdx.x) * 8;
  long stride = (long)gridDim.x * blockDim.x * 8;
  for (long i = i0; i < n; i += stride) {
    float4 f0 = *(const float4*)(in + i);
    float4 f1 = *(const float4*)(in + i + 4);
    bf16x8 v;
    v[0] = (__bf16)f0.x; v[1] = (__bf16)f0.y; v[2] = (__bf16)f0.z; v[3] = (__bf16)f0.w;
    v[4] = (__bf16)f1.x; v[5] = (__bf16)f1.y; v[6] = (__bf16)f1.z; v[7] = (__bf16)f1.w;
    *(bf16x8*)(out + i) = v;
  }
}

// ---- (int32 weight - zp) -> bf16, EXACT for |v|<=255 ----
__global__ void cvt_w_kernel(const int* __restrict__ w, const int* __restrict__ zp,
                             __bf16* __restrict__ out, int K, long n) {
  long i0 = ((long)blockIdx.x * blockDim.x + threadIdx.x) * 8;
  long stride = (long)gridDim.x * blockDim.x * 8;
  for (long i = i0; i < n; i += stride) {
    int4 a = *(const int4*)(w + i);
    int4 b = *(const int4*)(w + i + 4);
    int z = zp[i / K];
    bf16x8 v;
    v[0] = (__bf16)(float)(a.x - z); v[1] = (__bf16)(float)(a.y - z);
    v[2] = (__bf16)(float)(a.z - z); v[3] = (__bf16)(float)(a.w - z);
    v[4] = (__bf16)(float)(b.x - z); v[5] = (__bf16)(float)(b.y - z);
    v[6] = (__bf16)(float)(b.z - z); v[7] = (__bf16)(float)(b.w - z);
    *(bf16x8*)(out + i) = v;
  }
}

// ---- GEMM: C[m][n] = sum_k A[m][k]*W[n][k]; epilogue *scale[n] + bias[n] ----
// MODE 0: Asrc/Bsrc are preconverted bf16, staged via global_load_lds (width 16)
// MODE 1: Asrc fp32, Bsrc int32(+zp), reg-staged inline conversion (ws fallback)
template<int MODE>
__global__ __launch_bounds__(THREADS)
void qlin_gemm(const void* __restrict__ Asrc, const void* __restrict__ Bsrc,
               const int* __restrict__ zp,
               const float* __restrict__ scale, const float* __restrict__ bias,
               float* __restrict__ C, int M, int N, int K) {
  __shared__ alignas(16) __bf16 As[BM * BK];
  __shared__ alignas(16) __bf16 Bs[BN * BK];

  const int tid  = threadIdx.x;
  const int wave = tid >> 6;
  const int lane = tid & 63;

  // XCD-aware swizzle (bijective: grid % 8 == 0 for this shape)
  int bid = blockIdx.x, nwg = gridDim.x, swz = bid;
  if ((nwg & 7) == 0) swz = (bid & 7) * (nwg >> 3) + (bid >> 3);
  const int ntn = N / BN;
  const int tm = swz / ntn, tn = swz % ntn;
  const long row0 = (long)tm * BM;
  const long col0 = (long)tn * BN;

  const int wr = wave >> 1, wc = wave & 1;   // 2x2 waves, each owns 64x64

  f32x4 acc[4][4] = {};

  const __bf16* Ab = nullptr; const __bf16* Bb = nullptr;
  const float*  Af = nullptr; const int*    Bi = nullptr;
  if (MODE == 0) {
    Ab = (const __bf16*)Asrc + row0 * K;
    Bb = (const __bf16*)Bsrc + col0 * K;
  } else {
    Af = (const float*)Asrc;
    Bi = (const int*)Bsrc;
  }

  for (int kt = 0; kt < K; kt += BK) {
    if (MODE == 0) {
      // 16 chunks of 8 rows each (1024 B); wave handles 4 A-chunks + 4 B-chunks.
      // HW scatters lane l -> ldsbase + l*16B => row 8c+(l>>3), col (l&7)*8 elems.
      #pragma unroll
      for (int i = 0; i < 4; ++i) {
        const int c    = wave * 4 + i;
        const int r    = c * 8 + (lane >> 3);
        const int koff = (lane & 7) * 8;
        gload_lds16(Ab + (long)r * K + kt + koff, As + c * 512);
        gload_lds16(Bb + (long)r * K + kt + koff, Bs + c * 512);
      }
    } else {
      #pragma unroll
      for (int i = 0; i < 4; ++i) {
        const int flat = i * 2048 + tid * 8;
        const int r = flat >> 6, cc = flat & 63;
        const float* g = Af + (row0 + r) * (long)K + kt + cc;
        float4 f0 = *(const float4*)g;
        float4 f1 = *(const float4*)(g + 4);
        bf16x8 v;
        v[0] = (__bf16)f0.x; v[1] = (__bf16)f0.y; v[2] = (__bf16)f0.z; v[3] = (__bf16)f0.w;
        v[4] = (__bf16)f1.x; v[5] = (__bf16)f1.y; v[6] = (__bf16)f1.z; v[7] = (__bf16)f1.w;
        *(bf16x8*)(As + flat) = v;
      }
      #pragma unroll
      for (int i = 0; i < 4; ++i) {
        const int flat = i * 2048 + tid * 8;
        const int r = flat >> 6, cc = flat & 63;
        const long grow = col0 + r;
        const int z = zp[grow];
        const int* g = Bi + grow * (long)K + kt + cc;
        int4 a = *(const int4*)g;
        int4 b = *(const int4*)(g + 4);
        bf16x8 v;
        v[0] = (__bf16)(float)(a.x - z); v[1] = (__bf16)(float)(a.y - z);
        v[2] = (__bf16)(float)(a.z - z); v[3] = (__bf16)(float)(a.w - z);
        v[4] = (__bf16)(float)(b.x - z); v[5] = (__bf16)(float)(b.y - z);
        v[6] = (__bf16)(float)(b.z - z); v[7] = (__bf16)(float)(b.w - z);
        *(bf16x8*)(Bs + flat) = v;
      }
    }
    __syncthreads();   // drains vmcnt(0)+lgkmcnt(0) before barrier

    #pragma unroll
    for (int kk = 0; kk < 2; ++kk) {
      bf16x8 af[4], bfr[4];
      const int rsel = lane & 15;                 // A/B frag: row = lane&15
      const int csel = kk * 32 + (lane >> 4) * 8; // k-offset = (lane>>4)*8
      #pragma unroll
      for (int m = 0; m < 4; ++m)
        af[m] = *(const bf16x8*)(As + (wr * 64 + m * 16 + rsel) * BK + csel);
      #pragma unroll
      for (int n = 0; n < 4; ++n)
        bfr[n] = *(const bf16x8*)(Bs + (wc * 64 + n * 16 + rsel) * BK + csel);
      #pragma unroll
      for (int m = 0; m < 4; ++m)
        #pragma unroll
        for (int n = 0; n < 4; ++n)
          acc[m][n] = __builtin_amdgcn_mfma_f32_16x16x32_bf16(af[m], bfr[n], acc[m][n], 0, 0, 0);
    }
    __syncthreads();
  }

  // Epilogue. C/D layout (m89/m91): col = lane&15, row = (lane>>4)*4 + j
  float sc[4], bv[4];
  #pragma unroll
  for (int n = 0; n < 4; ++n) {
    const long gcol = col0 + wc * 64 + n * 16 + (lane & 15);
    sc[n] = scale[gcol];
    bv[n] = bias[gcol];
  }
  #pragma unroll
  for (int m = 0; m < 4; ++m) {
    const long grow = row0 + wr * 64 + m * 16 + ((lane >> 4) << 2);
    #pragma unroll
    for (int n = 0; n < 4; ++n) {
      const long gcol = col0 + wc * 64 + n * 16 + (lane & 15);
      float* o = C + grow * (long)N + gcol;
      #pragma unroll
      for (int j = 0; j < 4; ++j)
        o[(long)j * N] = acc[m][n][j] * sc[n] + bv[n];
    }
  }
}

extern "C" void kernel_launch(void* const* d_in, const int* in_sizes, int n_in,
                              void* d_out, int out_size, void* d_ws, size_t ws_size,
                              hipStream_t stream) {
  const float* x    = (const float*)d_in[0];
  const int*   wint = (const int*)d_in[1];
  const float* wsc  = (const float*)d_in[2];
  const int*   wzp  = (const int*)d_in[3];
  const float* bias = (const float*)d_in[4];
  float* out = (float*)d_out;

  const int N = in_sizes[4];            // 16384 (OUT)
  const int K = in_sizes[1] / N;        // 4096  (IN)
  const int M = in_sizes[0] / K;        // 8192  (B*S)

  const size_t xbytes = (size_t)M * K * sizeof(__bf16);
  const size_t wbytes = (size_t)N * K * sizeof(__bf16);
  const int grid = (M / BM) * (N / BN); // 64 * 128 = 8192 blocks

  if (ws_size >= xbytes + wbytes) {
    __bf16* xb = (__bf16*)d_ws;
    __bf16* wb = (__bf16*)((char*)d_ws + xbytes);
    cvt_x_kernel<<<2048, 256, 0, stream>>>(x, xb, (long)M * K);
    cvt_w_kernel<<<2048, 256, 0, stream>>>(wint, wzp, wb, K, (long)N * K);
    qlin_gemm<0><<<grid, THREADS, 0, stream>>>(xb, wb, nullptr, wsc, bias, out, M, N, K);
  } else {
    qlin_gemm<1><<<grid, THREADS, 0, stream>>>(x, wint, wzp, wsc, bias, out, M, N, K);
  }
}

// Round 2
// 1610.867 us; speedup vs baseline: 1.0382x; 1.0382x over previous
//
#include <hip/hip_runtime.h>
#include <hip/hip_bf16.h>

typedef __bf16 bf16x8 __attribute__((ext_vector_type(8)));
typedef float  f32x4  __attribute__((ext_vector_type(4)));

#define BM 128
#define BN 128
#define BK 64
#define THREADS 256

__device__ __forceinline__ void gload_lds16(const void* g, void* l) {
  __builtin_amdgcn_global_load_lds(
      (const __attribute__((address_space(1))) void*)g,
      (__attribute__((address_space(3))) void*)l, 16, 0, 0);
}

// ---- fp32 -> bf16 (RNE), 8 elems per thread-iter, grid-stride ----
__global__ void cvt_x_kernel(const float* __restrict__ in, __bf16* __restrict__ out, long n) {
  long i0 = ((long)blockIdx.x * blockDim.x + threadIdx.x) * 8;
  long stride = (long)gridDim.x * blockDim.x * 8;
  for (long i = i0; i < n; i += stride) {
    float4 f0 = *(const float4*)(in + i);
    float4 f1 = *(const float4*)(in + i + 4);
    bf16x8 v;
    v[0] = (__bf16)f0.x; v[1] = (__bf16)f0.y; v[2] = (__bf16)f0.z; v[3] = (__bf16)f0.w;
    v[4] = (__bf16)f1.x; v[5] = (__bf16)f1.y; v[6] = (__bf16)f1.z; v[7] = (__bf16)f1.w;
    *(bf16x8*)(out + i) = v;
  }
}

// ---- (int32 weight - zp) -> bf16, EXACT for |v|<=255 ----
__global__ void cvt_w_kernel(const int* __restrict__ w, const int* __restrict__ zp,
                             __bf16* __restrict__ out, int K, long n) {
  long i0 = ((long)blockIdx.x * blockDim.x + threadIdx.x) * 8;
  long stride = (long)gridDim.x * blockDim.x * 8;
  for (long i = i0; i < n; i += stride) {
    int4 a = *(const int4*)(w + i);
    int4 b = *(const int4*)(w + i + 4);
    int z = zp[i / K];
    bf16x8 v;
    v[0] = (__bf16)(float)(a.x - z); v[1] = (__bf16)(float)(a.y - z);
    v[2] = (__bf16)(float)(a.z - z); v[3] = (__bf16)(float)(a.w - z);
    v[4] = (__bf16)(float)(b.x - z); v[5] = (__bf16)(float)(b.y - z);
    v[6] = (__bf16)(float)(b.z - z); v[7] = (__bf16)(float)(b.w - z);
    *(bf16x8*)(out + i) = v;
  }
}

// ---- GEMM: C[m][n] = sum_k A[m][k]*W[n][k]; epilogue *scale[n] + bias[n] ----
// LDS tiles are XOR-swizzled (T2): 16B slot index s at row r stores k-slot
// s^(r&7). global_load_lds writes linearly, so the GLOBAL source address is
// pre-swizzled per-lane (rule #21); ds_read applies the same XOR.
template<int MODE>
__global__ __launch_bounds__(THREADS)
void qlin_gemm(const void* __restrict__ Asrc, const void* __restrict__ Bsrc,
               const int* __restrict__ zp,
               const float* __restrict__ scale, const float* __restrict__ bias,
               float* __restrict__ C, int M, int N, int K) {
  __shared__ alignas(16) __bf16 As[BM * BK];
  __shared__ alignas(16) __bf16 Bs[BN * BK];

  const int tid  = threadIdx.x;
  const int wave = tid >> 6;
  const int lane = tid & 63;

  // XCD-aware swizzle (bijective: grid % 8 == 0 for this shape)
  int bid = blockIdx.x, nwg = gridDim.x, swz = bid;
  if ((nwg & 7) == 0) swz = (bid & 7) * (nwg >> 3) + (bid >> 3);
  const int ntn = N / BN;
  const int tm = swz / ntn, tn = swz % ntn;
  const long row0 = (long)tm * BM;
  const long col0 = (long)tn * BN;

  const int wr = wave >> 1, wc = wave & 1;   // 2x2 waves, each owns 64x64

  f32x4 acc[4][4] = {};

  const __bf16* Ab = nullptr; const __bf16* Bb = nullptr;
  const float*  Af = nullptr; const int*    Bi = nullptr;
  if (MODE == 0) {
    Ab = (const __bf16*)Asrc + row0 * K;
    Bb = (const __bf16*)Bsrc + col0 * K;
  } else {
    Af = (const float*)Asrc;
    Bi = (const int*)Bsrc;
  }

  for (int kt = 0; kt < K; kt += BK) {
    if (MODE == 0) {
      // 16 chunks of 8 rows (1024 B each). HW: lane l -> ldsbase + l*16B
      // = (row 8c+(l>>3), slot l&7). Source k-slot pre-swizzled: (l&7)^(l>>3).
      const int kswz = ((lane & 7) ^ (lane >> 3)) * 8;  // elems
      #pragma unroll
      for (int i = 0; i < 4; ++i) {
        const int c = wave * 4 + i;
        const int r = c * 8 + (lane >> 3);
        gload_lds16(Ab + (long)r * K + kt + kswz, As + c * 512);
        gload_lds16(Bb + (long)r * K + kt + kswz, Bs + c * 512);
      }
    } else {
      #pragma unroll
      for (int i = 0; i < 4; ++i) {
        const int flat = i * 2048 + tid * 8;
        const int r = flat >> 6, cc = flat & 63;
        const int wcc = ((cc >> 3) ^ (r & 7)) << 3;     // swizzled write slot
        const float* g = Af + (row0 + r) * (long)K + kt + cc;
        float4 f0 = *(const float4*)g;
        float4 f1 = *(const float4*)(g + 4);
        bf16x8 v;
        v[0] = (__bf16)f0.x; v[1] = (__bf16)f0.y; v[2] = (__bf16)f0.z; v[3] = (__bf16)f0.w;
        v[4] = (__bf16)f1.x; v[5] = (__bf16)f1.y; v[6] = (__bf16)f1.z; v[7] = (__bf16)f1.w;
        *(bf16x8*)(As + r * BK + wcc) = v;
      }
      #pragma unroll
      for (int i = 0; i < 4; ++i) {
        const int flat = i * 2048 + tid * 8;
        const int r = flat >> 6, cc = flat & 63;
        const int wcc = ((cc >> 3) ^ (r & 7)) << 3;
        const long grow = col0 + r;
        const int z = zp[grow];
        const int* g = Bi + grow * (long)K + kt + cc;
        int4 a = *(const int4*)g;
        int4 b = *(const int4*)(g + 4);
        bf16x8 v;
        v[0] = (__bf16)(float)(a.x - z); v[1] = (__bf16)(float)(a.y - z);
        v[2] = (__bf16)(float)(a.z - z); v[3] = (__bf16)(float)(a.w - z);
        v[4] = (__bf16)(float)(b.x - z); v[5] = (__bf16)(float)(b.y - z);
        v[6] = (__bf16)(float)(b.z - z); v[7] = (__bf16)(float)(b.w - z);
        *(bf16x8*)(Bs + r * BK + wcc) = v;
      }
    }
    __syncthreads();

    #pragma unroll
    for (int kk = 0; kk < 2; ++kk) {
      bf16x8 af[4], bfr[4];
      const int rsel = lane & 15;            // fragment row within 16
      const int ks   = kk * 4 + (lane >> 4); // 8-elem k-slot within BK
      const int rdsl = (ks ^ (lane & 7)) << 3; // swizzled read offset (elems);
                                               // row&7 == lane&7 (bases %16==0)
      #pragma unroll
      for (int m = 0; m < 4; ++m)
        af[m] = *(const bf16x8*)(As + (wr * 64 + m * 16 + rsel) * BK + rdsl);
      #pragma unroll
      for (int n = 0; n < 4; ++n)
        bfr[n] = *(const bf16x8*)(Bs + (wc * 64 + n * 16 + rsel) * BK + rdsl);
      #pragma unroll
      for (int m = 0; m < 4; ++m)
        #pragma unroll
        for (int n = 0; n < 4; ++n)
          acc[m][n] = __builtin_amdgcn_mfma_f32_16x16x32_bf16(af[m], bfr[n], acc[m][n], 0, 0, 0);
    }
    __syncthreads();
  }

  // Epilogue. C/D layout (m89/m91): col = lane&15, row = (lane>>4)*4 + j
  float sc[4], bv[4];
  #pragma unroll
  for (int n = 0; n < 4; ++n) {
    const long gcol = col0 + wc * 64 + n * 16 + (lane & 15);
    sc[n] = scale[gcol];
    bv[n] = bias[gcol];
  }
  #pragma unroll
  for (int m = 0; m < 4; ++m) {
    const long grow = row0 + wr * 64 + m * 16 + ((lane >> 4) << 2);
    #pragma unroll
    for (int n = 0; n < 4; ++n) {
      const long gcol = col0 + wc * 64 + n * 16 + (lane & 15);
      float* o = C + grow * (long)N + gcol;
      #pragma unroll
      for (int j = 0; j < 4; ++j)
        o[(long)j * N] = acc[m][n][j] * sc[n] + bv[n];
    }
  }
}

extern "C" void kernel_launch(void* const* d_in, const int* in_sizes, int n_in,
                              void* d_out, int out_size, void* d_ws, size_t ws_size,
                              hipStream_t stream) {
  const float* x    = (const float*)d_in[0];
  const int*   wint = (const int*)d_in[1];
  const float* wsc  = (const float*)d_in[2];
  const int*   wzp  = (const int*)d_in[3];
  const float* bias = (const float*)d_in[4];
  float* out = (float*)d_out;

  const int N = in_sizes[4];            // 16384 (OUT)
  const int K = in_sizes[1] / N;        // 4096  (IN)
  const int M = in_sizes[0] / K;        // 8192  (B*S)

  const size_t xbytes = (size_t)M * K * sizeof(__bf16);
  const size_t wbytes = (size_t)N * K * sizeof(__bf16);
  const int grid = (M / BM) * (N / BN); // 64 * 128 = 8192 blocks

  if (ws_size >= xbytes + wbytes) {
    __bf16* xb = (__bf16*)d_ws;
    __bf16* wb = (__bf16*)((char*)d_ws + xbytes);
    cvt_x_kernel<<<2048, 256, 0, stream>>>(x, xb, (long)M * K);
    cvt_w_kernel<<<2048, 256, 0, stream>>>(wint, wzp, wb, K, (long)N * K);
    qlin_gemm<0><<<grid, THREADS, 0, stream>>>(xb, wb, nullptr, wsc, bias, out, M, N, K);
  } else {
    qlin_gemm<1><<<grid, THREADS, 0, stream>>>(x, wint, wzp, wsc, bias, out, M, N, K);
  }
}

// Round 3
// 1531.422 us; speedup vs baseline: 1.0920x; 1.0519x over previous
//
#include <hip/hip_runtime.h>
#include <hip/hip_bf16.h>

typedef __bf16 bf16x8 __attribute__((ext_vector_type(8)));
typedef float  f32x4  __attribute__((ext_vector_type(4)));

#define BM 256
#define BN 256
#define BK 64
#define THREADS 512

__device__ __forceinline__ void gload_lds16(const void* g, void* l) {
  __builtin_amdgcn_global_load_lds(
      (const __attribute__((address_space(1))) void*)g,
      (__attribute__((address_space(3))) void*)l, 16, 0, 0);
}

template<int N> __device__ __forceinline__ void vmwait() {
  if constexpr (N == 0)       asm volatile("s_waitcnt vmcnt(0)" ::: "memory");
  else if constexpr (N == 2)  asm volatile("s_waitcnt vmcnt(2)" ::: "memory");
  else if constexpr (N == 8)  asm volatile("s_waitcnt vmcnt(8)" ::: "memory");
  else if constexpr (N == 10) asm volatile("s_waitcnt vmcnt(10)" ::: "memory");
}

// ---- fp32 -> bf16 (RNE) ----
__global__ void cvt_x_kernel(const float* __restrict__ in, __bf16* __restrict__ out, long n) {
  long i0 = ((long)blockIdx.x * blockDim.x + threadIdx.x) * 8;
  long stride = (long)gridDim.x * blockDim.x * 8;
  for (long i = i0; i < n; i += stride) {
    float4 f0 = *(const float4*)(in + i);
    float4 f1 = *(const float4*)(in + i + 4);
    bf16x8 v;
    v[0] = (__bf16)f0.x; v[1] = (__bf16)f0.y; v[2] = (__bf16)f0.z; v[3] = (__bf16)f0.w;
    v[4] = (__bf16)f1.x; v[5] = (__bf16)f1.y; v[6] = (__bf16)f1.z; v[7] = (__bf16)f1.w;
    *(bf16x8*)(out + i) = v;
  }
}

// ---- (int32 weight - zp) -> bf16, EXACT for |v|<=255 ----
__global__ void cvt_w_kernel(const int* __restrict__ w, const int* __restrict__ zp,
                             __bf16* __restrict__ out, int K, long n) {
  long i0 = ((long)blockIdx.x * blockDim.x + threadIdx.x) * 8;
  long stride = (long)gridDim.x * blockDim.x * 8;
  for (long i = i0; i < n; i += stride) {
    int4 a = *(const int4*)(w + i);
    int4 b = *(const int4*)(w + i + 4);
    int z = zp[i / K];
    bf16x8 v;
    v[0] = (__bf16)(float)(a.x - z); v[1] = (__bf16)(float)(a.y - z);
    v[2] = (__bf16)(float)(a.z - z); v[3] = (__bf16)(float)(a.w - z);
    v[4] = (__bf16)(float)(b.x - z); v[5] = (__bf16)(float)(b.y - z);
    v[6] = (__bf16)(float)(b.z - z); v[7] = (__bf16)(float)(b.w - z);
    *(bf16x8*)(out + i) = v;
  }
}

// ============ 256x256 8-phase-style GEMM (T2+T3+T4+T5+T1) ============
// C[m][n] = sum_k A[m][k]*B[n][k]; epilogue *scale[n]+bias[n].
// LDS XOR-swizzle: 16B slot s at row r holds k-slot s^(r&7); achieved with
// linear LDS dest + pre-swizzled global source (rule #21).
// Per K-tile: 4 phases = 4 m-quadrants. B-frags -> regs in phase 0.
// Chunk c = 64 rows (1 gload_lds/wave). Stage schedule (tile t, buf b=t&1):
//   ph0: A1,A3(t+1)->b^1   ph1: B0,B1(t+2)->b   ph2: B2,B3(t+2)->b
//   ph3: A0,A2(t+2)->b     (regions verified dead at issue time)
// Counted vmcnt BEFORE the barrier preceding dependent reads:
//   end-ph3: vmcnt(8)  (next ph0 reads B(t+1),A0,A2(t+1))
//   end-ph1: vmcnt(10) (ph2 reads A1,A3(t))
__global__ __launch_bounds__(THREADS, 2)
void qlin_gemm(const __bf16* __restrict__ A, const __bf16* __restrict__ B,
               const float* __restrict__ scale, const float* __restrict__ bias,
               float* __restrict__ C, int M, int N, int K) {
  __shared__ alignas(16) __bf16 As[2][BM * BK];
  __shared__ alignas(16) __bf16 Bs[2][BN * BK];

  const int tid  = threadIdx.x;
  const int wave = tid >> 6;
  const int lane = tid & 63;
  const int wm = wave >> 2, wn = wave & 3;       // 2x4 waves; per-wave 128x64

  int bid = blockIdx.x, nwg = gridDim.x, swz = bid;
  if ((nwg & 7) == 0) swz = (bid & 7) * (nwg >> 3) + (bid >> 3);
  const int ntn = N / BN;
  const long row0 = (long)(swz / ntn) * BM;
  const long col0 = (long)(swz % ntn) * BN;

  const __bf16* Ag = A + row0 * (long)K;
  const __bf16* Bg = B + col0 * (long)K;

  // staging: chunk c = rows [c*64, c*64+64); wave-uniform LDS base; HW adds lane*16B
  const int srow = wave * 8 + (lane >> 3);            // row within chunk
  const int kswz = ((lane & 7) ^ (lane >> 3)) * 8;    // pre-swizzled k elems

#define STAGE_A(b, c, kt) gload_lds16(Ag + (long)((c)*64 + srow) * K + (kt) + kswz, \
                                      &As[b][(c)*4096 + wave*512])
#define STAGE_B(b, c, kt) gload_lds16(Bg + (long)((c)*64 + srow) * K + (kt) + kswz, \
                                      &Bs[b][(c)*4096 + wave*512])

  const int rsel = lane & 15;
  const int ksl  = lane >> 4;    // 0..3
  const int lan7 = lane & 7;     // == frag-row & 7 (bases are multiples of 16)

  f32x4  acc[8][4] = {};
  bf16x8 bf[4][2];               // B frags [n][kk], loaded each ph0

#define PHASE(qq, bb, DO_B, ENDW, ...)                                          \
  {                                                                             \
    bf16x8 af[2][2];                                                            \
    _Pragma("unroll")                                                           \
    for (int mi = 0; mi < 2; ++mi)                                              \
      _Pragma("unroll")                                                         \
      for (int kk = 0; kk < 2; ++kk)                                            \
        af[mi][kk] = *(const bf16x8*)&As[bb][(wm*128 + (2*(qq)+mi)*16 + rsel)*BK \
                                             + ((((kk<<2)+ksl) ^ lan7) << 3)];  \
    if (DO_B) {                                                                 \
      _Pragma("unroll")                                                         \
      for (int n = 0; n < 4; ++n)                                               \
        _Pragma("unroll")                                                       \
        for (int kk = 0; kk < 2; ++kk)                                          \
          bf[n][kk] = *(const bf16x8*)&Bs[bb][(wn*64 + n*16 + rsel)*BK          \
                                              + ((((kk<<2)+ksl) ^ lan7) << 3)]; \
    }                                                                           \
    __VA_ARGS__;                                                                \
    __builtin_amdgcn_s_barrier();                                               \
    asm volatile("s_waitcnt lgkmcnt(0)" ::: "memory");                          \
    __builtin_amdgcn_s_setprio(1);                                              \
    _Pragma("unroll")                                                           \
    for (int kk = 0; kk < 2; ++kk)                                              \
      _Pragma("unroll")                                                         \
      for (int mi = 0; mi < 2; ++mi)                                            \
        _Pragma("unroll")                                                       \
        for (int n = 0; n < 4; ++n)                                             \
          acc[2*(qq)+mi][n] = __builtin_amdgcn_mfma_f32_16x16x32_bf16(          \
              af[mi][kk], bf[n][kk], acc[2*(qq)+mi][n], 0, 0, 0);               \
    __builtin_amdgcn_s_setprio(0);                                              \
    ENDW;                                                                       \
    __builtin_amdgcn_s_barrier();                                               \
  }

  const int NT = K / BK;   // 64 for this shape (>= 3 required)

  // Prologue: tile0 (8 chunks) + tile1 (first 6), issue order = retirement order.
  STAGE_B(0,0,0); STAGE_B(0,1,0); STAGE_B(0,2,0); STAGE_B(0,3,0);
  STAGE_A(0,0,0); STAGE_A(0,2,0);
  STAGE_A(0,1,0); STAGE_A(0,3,0);
  STAGE_B(1,0,BK); STAGE_B(1,1,BK); STAGE_B(1,2,BK); STAGE_B(1,3,BK);
  STAGE_A(1,0,BK); STAGE_A(1,2,BK);
  vmwait<8>();                         // oldest 6 (B(0),A0,A2(0)) retired
  __builtin_amdgcn_s_barrier();

  for (int t = 0; t < NT - 2; ++t) {
    const int b = t & 1;
    const long kt1 = (long)(t + 1) * BK;
    const long kt2 = (long)(t + 2) * BK;
    PHASE(0, b, 1, (void)0,     STAGE_A(b^1, 1, kt1); STAGE_A(b^1, 3, kt1))
    PHASE(1, b, 0, vmwait<10>(), STAGE_B(b, 0, kt2); STAGE_B(b, 1, kt2))
    PHASE(2, b, 0, (void)0,     STAGE_B(b, 2, kt2); STAGE_B(b, 3, kt2))
    PHASE(3, b, 0, vmwait<8>(),  STAGE_A(b, 0, kt2); STAGE_A(b, 2, kt2))
  }
  {  // t = NT-2: only stage tile NT-1's A1,A3
    const int b = (NT - 2) & 1;
    const long kt1 = (long)(NT - 1) * BK;
    PHASE(0, b, 1, (void)0, STAGE_A(b^1, 1, kt1); STAGE_A(b^1, 3, kt1))
    PHASE(1, b, 0, vmwait<8>(), (void)0)
    PHASE(2, b, 0, (void)0, (void)0)
    PHASE(3, b, 0, vmwait<2>(), (void)0)
  }
  {  // t = NT-1: drain
    const int b = (NT - 1) & 1;
    PHASE(0, b, 1, (void)0, (void)0)
    PHASE(1, b, 0, vmwait<0>(), (void)0)
    PHASE(2, b, 0, (void)0, (void)0)
    PHASE(3, b, 0, (void)0, (void)0)
  }
#undef PHASE
#undef STAGE_A
#undef STAGE_B

  // Epilogue. C/D: col = lane&15, row = (lane>>4)*4 + j
  float sc[4], bv[4];
  #pragma unroll
  for (int n = 0; n < 4; ++n) {
    const long gcol = col0 + wn * 64 + n * 16 + rsel;
    sc[n] = scale[gcol];
    bv[n] = bias[gcol];
  }
  #pragma unroll
  for (int m = 0; m < 8; ++m) {
    const long grow = row0 + wm * 128 + m * 16 + ksl * 4;
    #pragma unroll
    for (int n = 0; n < 4; ++n) {
      const long gcol = col0 + wn * 64 + n * 16 + rsel;
      float* o = C + grow * (long)N + gcol;
      #pragma unroll
      for (int j = 0; j < 4; ++j)
        o[(long)j * N] = acc[m][n][j] * sc[n] + bv[n];
    }
  }
}

// ---- fallback (ws too small): reg-staged 128x128, inline dequant ----
__global__ __launch_bounds__(256)
void qlin_gemm_small(const float* __restrict__ Af, const int* __restrict__ Bi,
                     const int* __restrict__ zp,
                     const float* __restrict__ scale, const float* __restrict__ bias,
                     float* __restrict__ C, int M, int N, int K) {
  __shared__ alignas(16) __bf16 As[128 * 64];
  __shared__ alignas(16) __bf16 Bs[128 * 64];
  const int tid = threadIdx.x, wave = tid >> 6, lane = tid & 63;
  int bid = blockIdx.x, nwg = gridDim.x, swz = bid;
  if ((nwg & 7) == 0) swz = (bid & 7) * (nwg >> 3) + (bid >> 3);
  const int ntn = N / 128;
  const long row0 = (long)(swz / ntn) * 128, col0 = (long)(swz % ntn) * 128;
  const int wr = wave >> 1, wc = wave & 1;
  f32x4 acc[4][4] = {};
  for (int kt = 0; kt < K; kt += 64) {
    #pragma unroll
    for (int i = 0; i < 4; ++i) {
      const int flat = i * 2048 + tid * 8;
      const int r = flat >> 6, cc = flat & 63;
      const int wcc = ((cc >> 3) ^ (r & 7)) << 3;
      const float* g = Af + (row0 + r) * (long)K + kt + cc;
      float4 f0 = *(const float4*)g; float4 f1 = *(const float4*)(g + 4);
      bf16x8 v;
      v[0]=(__bf16)f0.x; v[1]=(__bf16)f0.y; v[2]=(__bf16)f0.z; v[3]=(__bf16)f0.w;
      v[4]=(__bf16)f1.x; v[5]=(__bf16)f1.y; v[6]=(__bf16)f1.z; v[7]=(__bf16)f1.w;
      *(bf16x8*)(As + r * 64 + wcc) = v;
    }
    #pragma unroll
    for (int i = 0; i < 4; ++i) {
      const int flat = i * 2048 + tid * 8;
      const int r = flat >> 6, cc = flat & 63;
      const int wcc = ((cc >> 3) ^ (r & 7)) << 3;
      const long grow = col0 + r;
      const int z = zp[grow];
      const int* g = Bi + grow * (long)K + kt + cc;
      int4 a = *(const int4*)g; int4 b = *(const int4*)(g + 4);
      bf16x8 v;
      v[0]=(__bf16)(float)(a.x-z); v[1]=(__bf16)(float)(a.y-z);
      v[2]=(__bf16)(float)(a.z-z); v[3]=(__bf16)(float)(a.w-z);
      v[4]=(__bf16)(float)(b.x-z); v[5]=(__bf16)(float)(b.y-z);
      v[6]=(__bf16)(float)(b.z-z); v[7]=(__bf16)(float)(b.w-z);
      *(bf16x8*)(Bs + r * 64 + wcc) = v;
    }
    __syncthreads();
    #pragma unroll
    for (int kk = 0; kk < 2; ++kk) {
      bf16x8 af[4], bfr[4];
      const int rs = lane & 15, ks = kk * 4 + (lane >> 4);
      const int rd = (ks ^ (lane & 7)) << 3;
      #pragma unroll
      for (int m = 0; m < 4; ++m) af[m] = *(const bf16x8*)(As + (wr*64 + m*16 + rs)*64 + rd);
      #pragma unroll
      for (int n = 0; n < 4; ++n) bfr[n] = *(const bf16x8*)(Bs + (wc*64 + n*16 + rs)*64 + rd);
      #pragma unroll
      for (int m = 0; m < 4; ++m)
        #pragma unroll
        for (int n = 0; n < 4; ++n)
          acc[m][n] = __builtin_amdgcn_mfma_f32_16x16x32_bf16(af[m], bfr[n], acc[m][n], 0, 0, 0);
    }
    __syncthreads();
  }
  #pragma unroll
  for (int m = 0; m < 4; ++m) {
    const long grow = row0 + wr * 64 + m * 16 + ((lane >> 4) << 2);
    #pragma unroll
    for (int n = 0; n < 4; ++n) {
      const long gcol = col0 + wc * 64 + n * 16 + (lane & 15);
      const float s = scale[gcol], bb2 = bias[gcol];
      float* o = C + grow * (long)N + gcol;
      #pragma unroll
      for (int j = 0; j < 4; ++j) o[(long)j * N] = acc[m][n][j] * s + bb2;
    }
  }
}

extern "C" void kernel_launch(void* const* d_in, const int* in_sizes, int n_in,
                              void* d_out, int out_size, void* d_ws, size_t ws_size,
                              hipStream_t stream) {
  const float* x    = (const float*)d_in[0];
  const int*   wint = (const int*)d_in[1];
  const float* wsc  = (const float*)d_in[2];
  const int*   wzp  = (const int*)d_in[3];
  const float* bias = (const float*)d_in[4];
  float* out = (float*)d_out;

  const int N = in_sizes[4];            // 16384 (OUT)
  const int K = in_sizes[1] / N;        // 4096  (IN)
  const int M = in_sizes[0] / K;        // 8192  (B*S)

  const size_t xbytes = (size_t)M * K * sizeof(__bf16);
  const size_t wbytes = (size_t)N * K * sizeof(__bf16);

  if (ws_size >= xbytes + wbytes && (M % BM) == 0 && (N % BN) == 0 && (K % BK) == 0 && K / BK >= 3) {
    __bf16* xb = (__bf16*)d_ws;
    __bf16* wb = (__bf16*)((char*)d_ws + xbytes);
    cvt_x_kernel<<<2048, 256, 0, stream>>>(x, xb, (long)M * K);
    cvt_w_kernel<<<2048, 256, 0, stream>>>(wint, wzp, wb, K, (long)N * K);
    const int grid = (M / BM) * (N / BN); // 32 * 64 = 2048
    qlin_gemm<<<grid, THREADS, 0, stream>>>(xb, wb, wsc, bias, out, M, N, K);
  } else {
    const int grid = (M / 128) * (N / 128);
    qlin_gemm_small<<<grid, 256, 0, stream>>>(x, wint, wzp, wsc, bias, out, M, N, K);
  }
}